// Round 4
// baseline (1544.384 us; speedup 1.0000x reference)
//
#include <hip/hip_runtime.h>
#include <stdint.h>

#define H 2048
#define BTOK 16384   // B*S
#define NSEG 2048    // B*SPANS_PER_ITEM
#define SPANS 512
#define SEQ 4096

typedef __attribute__((ext_vector_type(8))) short bf16x8;
typedef __attribute__((ext_vector_type(4))) float f32x4;

__device__ __forceinline__ short f2bf(float f) {
  union { float f; uint32_t u; } x; x.f = f;
  uint32_t r = x.u + 0x7FFFu + ((x.u >> 16) & 1u);
  return (short)(uint16_t)(r >> 16);
}
__device__ __forceinline__ float bf2f(short h) {
  union { uint32_t u; float f; } x; x.u = ((uint32_t)(uint16_t)h) << 16;
  return x.f;
}

typedef __attribute__((address_space(1))) const void* gas_t;
typedef __attribute__((address_space(3))) void* las_t;
__device__ __forceinline__ void stage16(const void* g, void* l) {
  __builtin_amdgcn_global_load_lds((gas_t)g, (las_t)l, 16, 0, 0);
}

// ---------------- int64/int32 id detection + normalization ----------------
__global__ void detect_ids_kernel(const void* __restrict__ ids, int* __restrict__ flag) {
  __shared__ int any;
  if (threadIdx.x == 0) any = 0;
  __syncthreads();
  const long long* p = (const long long*)ids;
  int bad = 0;
  for (int i = threadIdx.x; i < 8192; i += 256) {   // 64KB: in-bounds for both layouts
    long long v = p[i];
    if (v < 0 || v >= 32000) bad = 1;
  }
  if (bad) any = 1;
  __syncthreads();
  if (threadIdx.x == 0) flag[0] = any;              // 1 -> storage is int32
}

__global__ void ids_norm_kernel(const void* __restrict__ ids, const int* __restrict__ flag,
                                int* __restrict__ ids32) {
  int i = blockIdx.x * 256 + threadIdx.x;
  if (flag[0]) {
    ids32[i] = ((const int*)ids)[i];
  } else {
    ids32[i] = (int)((const long long*)ids)[i];
  }
}

// ---------------- weight transpose + bf16 convert: Wt[n][k] = bf16(W[k][n]) ----------------
__global__ __launch_bounds__(256) void wconv_kernel(const float* __restrict__ W,
                                                    short* __restrict__ Wt, int K, int N) {
  __shared__ float t[32][33];
  int nt = N >> 5;
  int ti = blockIdx.x / nt;  // K tile
  int tj = blockIdx.x % nt;  // N tile
  int x = threadIdx.x & 31;
  int y = threadIdx.x >> 5;  // 0..7
  #pragma unroll
  for (int yy = 0; yy < 32; yy += 8)
    t[yy + y][x] = W[(size_t)(ti * 32 + yy + y) * N + tj * 32 + x];
  __syncthreads();
  #pragma unroll
  for (int yy = 0; yy < 32; yy += 8)
    Wt[(size_t)(tj * 32 + yy + y) * K + ti * 32 + x] = f2bf(t[x][yy + y]);
}

// ---------------- embedding gather -> bf16 ----------------
__global__ __launch_bounds__(256) void embed_kernel(const int* __restrict__ ids32,
                                                    const float* __restrict__ table,
                                                    short* __restrict__ emb) {
  int m = blockIdx.x;
  int row = ids32[m];
  const float4* src = (const float4*)(table + (size_t)row * H) + threadIdx.x * 2;
  float4 a = src[0], b = src[1];
  bf16x8 o;
  o[0] = f2bf(a.x); o[1] = f2bf(a.y); o[2] = f2bf(a.z); o[3] = f2bf(a.w);
  o[4] = f2bf(b.x); o[5] = f2bf(b.y); o[6] = f2bf(b.z); o[7] = f2bf(b.w);
  *(bf16x8*)(emb + (size_t)m * H + threadIdx.x * 8) = o;
}

// ---------------- MFMA GEMM: C[m,n] = A[m,:K] @ B[:K,n], Bt is [N][K] bf16 ----------------
// EPI 0: GELU -> bf16    EPI 1: + emb residual -> bf16    EPI 2: plain -> bf16
// EPI 3: gate = sigmoid(x)*mask; combined = (1-g)*tok + g*span_emb; write f32 outs
#define BM 128
#define BN 128
#define BK 32

template<int EPI>
__global__ __launch_bounds__(256, 2) void gemm_kernel(
    const short* __restrict__ A, const short* __restrict__ A2, int K1,
    const short* __restrict__ Bt, const float* __restrict__ bias,
    int M, int N, int K,
    const short* __restrict__ embres, short* __restrict__ outb,
    const int* __restrict__ span_ids, const int* __restrict__ valid,
    const short* __restrict__ tokp, const short* __restrict__ enh,
    float* __restrict__ outC, float* __restrict__ outG) {
  __shared__ __align__(16) short lA[BM * BK];
  __shared__ __align__(16) short lB[BN * BK];
  const int tid = threadIdx.x;
  const int wave = tid >> 6;
  const int lane = tid & 63;
  const int MB = M / BM;
  // Bijective XCD-aware swizzle (T1): nwg is always a multiple of 8 here.
  // Default dispatch round-robins consecutive bids across the 8 XCD L2s;
  // this remap gives each XCD a contiguous tile chunk -> B-panel L2 reuse.
  const int nwg = gridDim.x;
  const int cpx = nwg >> 3;
  const int swz = (blockIdx.x & 7) * cpx + (blockIdx.x >> 3);
  const int bm = swz % MB;
  const int bn = swz / MB;
  const int wm = wave >> 1, wn = wave & 1;

  f32x4 zero4 = {0.f, 0.f, 0.f, 0.f};
  f32x4 acc[4][4];
  #pragma unroll
  for (int i = 0; i < 4; ++i)
    #pragma unroll
    for (int j = 0; j < 4; ++j) acc[i][j] = zero4;

  const int sr = wave * 32 + (lane >> 2);  // staging row within tile (j=0 group)
  const int kc = (lane & 3) * 8;           // staging k-chunk (bf16 elems)
  const int ar0 = bm * BM + sr;
  const int br0 = bn * BN + sr;
  short* ldsA0 = &lA[(wave * 32) * BK];
  short* ldsA1 = &lA[(wave * 32 + 16) * BK];
  short* ldsB0 = &lB[(wave * 32) * BK];
  short* ldsB1 = &lB[(wave * 32 + 16) * BK];

  const int clr = lane & 15;          // fragment row (A) / col (B) / col (C)
  const int clk = (lane >> 4) * 8;    // fragment k offset

  for (int kk = 0; kk < K; kk += BK) {
    const short* Ab; int ko, as_;
    if (kk < K1) { Ab = A; ko = kk; as_ = K1; }
    else         { Ab = A2; ko = kk - K1; as_ = K - K1; }
    __syncthreads();
    stage16(Ab + (size_t)ar0 * as_ + ko + kc, ldsA0);
    stage16(Ab + (size_t)(ar0 + 16) * as_ + ko + kc, ldsA1);
    stage16(Bt + (size_t)br0 * K + kk + kc, ldsB0);
    stage16(Bt + (size_t)(br0 + 16) * K + kk + kc, ldsB1);
    __syncthreads();

    bf16x8 af[4], bfr[4];
    #pragma unroll
    for (int mi = 0; mi < 4; ++mi)
      af[mi] = *(const bf16x8*)&lA[(wm * 64 + mi * 16 + clr) * BK + clk];
    #pragma unroll
    for (int ni = 0; ni < 4; ++ni)
      bfr[ni] = *(const bf16x8*)&lB[(wn * 64 + ni * 16 + clr) * BK + clk];
    #pragma unroll
    for (int mi = 0; mi < 4; ++mi)
      #pragma unroll
      for (int ni = 0; ni < 4; ++ni)
        acc[mi][ni] = __builtin_amdgcn_mfma_f32_16x16x32_bf16(af[mi], bfr[ni], acc[mi][ni], 0, 0, 0);
  }

  const int lg = lane >> 4;
  const int rb = bm * BM + wm * 64;
  const int cb = bn * BN + wn * 64;
  #pragma unroll
  for (int ni = 0; ni < 4; ++ni) {
    const int c = cb + ni * 16 + clr;
    const float bv = bias[c];
    #pragma unroll
    for (int mi = 0; mi < 4; ++mi) {
      const int r0e = rb + mi * 16 + lg * 4;
      #pragma unroll
      for (int j = 0; j < 4; ++j) {
        const int r = r0e + j;
        float x = acc[mi][ni][j] + bv;
        if (EPI == 0) {
          float g = 0.5f * x * (1.f + erff(x * 0.70710678118654752f));
          outb[(size_t)r * N + c] = f2bf(g);
        } else if (EPI == 1) {
          x += bf2f(embres[(size_t)r * N + c]);
          outb[(size_t)r * N + c] = f2bf(x);
        } else if (EPI == 2) {
          outb[(size_t)r * N + c] = f2bf(x);
        } else {
          const int seg = ((r >> 12) << 9) + span_ids[r];
          const int v = valid[seg];
          const float g = v ? (1.f / (1.f + __expf(-x))) : 0.f;
          const float te = bf2f(tokp[(size_t)r * H + c]);
          const float se = v ? bf2f(enh[(size_t)seg * H + c]) : te;
          outC[(size_t)r * H + c] = (1.f - g) * te + g * se;
          outG[(size_t)r * H + c] = g;
        }
      }
    }
  }
}

// ---------------- per-segment mean pool + type embedding ----------------
__global__ __launch_bounds__(256) void pool_kernel(
    const short* __restrict__ tok, const int* __restrict__ span_ids,
    const int* __restrict__ span_type_ids, const float* __restrict__ type_table,
    short* __restrict__ pooled, int* __restrict__ valid) {
  __shared__ int list[SEQ];
  __shared__ int nmatch;
  const int gseg = blockIdx.x;
  const int b = gseg >> 9;
  const int sp = gseg & 511;
  if (threadIdx.x == 0) nmatch = 0;
  __syncthreads();
  const int* sid = span_ids + b * SEQ;
  for (int s = threadIdx.x; s < SEQ; s += 256)
    if (sid[s] == sp) list[atomicAdd(&nmatch, 1)] = s;
  __syncthreads();
  const int n = nmatch;
  float accv[8] = {0, 0, 0, 0, 0, 0, 0, 0};
  const int d0 = threadIdx.x * 8;
  for (int i = 0; i < n; ++i) {
    const int s = list[i];
    bf16x8 v = *(const bf16x8*)(tok + ((size_t)(b * SEQ + s)) * H + d0);
    #pragma unroll
    for (int j = 0; j < 8; ++j) accv[j] += bf2f(v[j]);
  }
  const float inv = 1.f / (float)(n > 0 ? n : 1);
  const int t = span_type_ids[gseg];
  const float* tt = type_table + (size_t)t * H + d0;
  bf16x8 o;
  #pragma unroll
  for (int j = 0; j < 8; ++j) o[j] = f2bf(accv[j] * inv + tt[j]);
  *(bf16x8*)(pooled + (size_t)gseg * H + d0) = o;
  if (threadIdx.x == 0) valid[gseg] = (n > 1) ? 1 : 0;
}

// ---------------- per-token span_emb select + LayerNorm + mask ----------------
__global__ __launch_bounds__(256) void ln_kernel(
    const short* __restrict__ tok, const short* __restrict__ enh,
    const int* __restrict__ span_ids, const int* __restrict__ valid,
    const float* __restrict__ ln_g, const float* __restrict__ ln_b,
    short* __restrict__ normout, float* __restrict__ maskout) {
  const int m = blockIdx.x;
  const int b = m >> 12;
  const int seg = (b << 9) + span_ids[m];
  const int v = valid[seg];
  const short* src = v ? (enh + (size_t)seg * H) : (tok + (size_t)m * H);
  const int d0 = threadIdx.x * 8;
  bf16x8 raw = *(const bf16x8*)(src + d0);
  float vals[8];
  float s = 0.f, s2 = 0.f;
  #pragma unroll
  for (int j = 0; j < 8; ++j) { float f = bf2f(raw[j]); vals[j] = f; s += f; s2 += f * f; }
  #pragma unroll
  for (int o = 32; o > 0; o >>= 1) { s += __shfl_down(s, o); s2 += __shfl_down(s2, o); }
  __shared__ float red[8];
  const int wv = threadIdx.x >> 6, ln = threadIdx.x & 63;
  if (ln == 0) { red[wv] = s; red[4 + wv] = s2; }
  __syncthreads();
  const float S = red[0] + red[1] + red[2] + red[3];
  const float S2 = red[4] + red[5] + red[6] + red[7];
  const float mean = S * (1.f / H);
  const float var = S2 * (1.f / H) - mean * mean;
  const float rstd = rsqrtf(var + 1e-5f);
  const float4* gp = (const float4*)(ln_g + d0);
  const float4* bp = (const float4*)(ln_b + d0);
  float4 g0 = gp[0], g1 = gp[1], b0 = bp[0], b1 = bp[1];
  const float gs[8] = {g0.x, g0.y, g0.z, g0.w, g1.x, g1.y, g1.z, g1.w};
  const float bs[8] = {b0.x, b0.y, b0.z, b0.w, b1.x, b1.y, b1.z, b1.w};
  bf16x8 o;
  #pragma unroll
  for (int j = 0; j < 8; ++j) o[j] = f2bf((vals[j] - mean) * rstd * gs[j] + bs[j]);
  *(bf16x8*)(normout + (size_t)m * H + d0) = o;
  if (threadIdx.x == 0) maskout[m] = v ? 1.f : 0.f;
}

extern "C" void kernel_launch(void* const* d_in, const int* in_sizes, int n_in,
                              void* d_out, int out_size, void* d_ws, size_t ws_size,
                              hipStream_t stream) {
  const void* input_ids = d_in[0];
  const int* span_ids = (const int*)d_in[1];
  const int* span_type_ids = (const int*)d_in[2];
  const float* tok_table = (const float*)d_in[3];
  const float* W1 = (const float*)d_in[4];
  const float* b1 = (const float*)d_in[5];
  const float* W2 = (const float*)d_in[6];
  const float* b2 = (const float*)d_in[7];
  const float* type_table = (const float*)d_in[8];
  const float* Wp = (const float*)d_in[9];
  const float* bp = (const float*)d_in[10];
  const float* ln_g = (const float*)d_in[11];
  const float* ln_b = (const float*)d_in[12];
  const float* Wg = (const float*)d_in[13];
  const float* bg = (const float*)d_in[14];

  char* ws = (char*)d_ws;
  size_t off = 0;
  auto alloc = [&](size_t bytes) -> void* {
    void* p = ws + off;
    off += (bytes + 255) & ~(size_t)255;
    return p;
  };
  short* emb = (short*)alloc((size_t)BTOK * H * 2);
  short* h1 = (short*)alloc((size_t)BTOK * H * 2);   // reused as `norm` after gemm2
  short* tokb = (short*)alloc((size_t)BTOK * H * 2);
  short* W1t = (short*)alloc((size_t)H * H * 2);
  short* W2t = (short*)alloc((size_t)H * H * 2);
  short* Wpt = (short*)alloc((size_t)H * H * 2);
  short* Wgt = (short*)alloc((size_t)2 * H * H * 2);
  short* pooledA = (short*)alloc((size_t)NSEG * H * 2);
  short* enh = (short*)alloc((size_t)NSEG * H * 2);
  int* validf = (int*)alloc(NSEG * 4);
  int* ids32 = (int*)alloc(BTOK * 4);
  int* flag = (int*)alloc(256);

  float* outC = (float*)d_out;
  float* outG = outC + (size_t)BTOK * H;
  float* outM = outG + (size_t)BTOK * H;

  detect_ids_kernel<<<1, 256, 0, stream>>>(input_ids, flag);
  ids_norm_kernel<<<BTOK / 256, 256, 0, stream>>>(input_ids, flag, ids32);
  wconv_kernel<<<(H / 32) * (H / 32), 256, 0, stream>>>(W1, W1t, H, H);
  wconv_kernel<<<(H / 32) * (H / 32), 256, 0, stream>>>(W2, W2t, H, H);
  wconv_kernel<<<(H / 32) * (H / 32), 256, 0, stream>>>(Wp, Wpt, H, H);
  wconv_kernel<<<(2 * H / 32) * (H / 32), 256, 0, stream>>>(Wg, Wgt, 2 * H, H);
  embed_kernel<<<BTOK, 256, 0, stream>>>(ids32, tok_table, emb);

  // h1 = gelu(emb @ W1 + b1)
  gemm_kernel<0><<<(BTOK / BM) * (H / BN), 256, 0, stream>>>(
      emb, emb, H, W1t, b1, BTOK, H, H,
      nullptr, h1, nullptr, nullptr, nullptr, nullptr, nullptr, nullptr);
  // tok = emb + h1 @ W2 + b2
  gemm_kernel<1><<<(BTOK / BM) * (H / BN), 256, 0, stream>>>(
      h1, h1, H, W2t, b2, BTOK, H, H,
      emb, tokb, nullptr, nullptr, nullptr, nullptr, nullptr, nullptr);
  // pooled+type, valid
  pool_kernel<<<NSEG, 256, 0, stream>>>(tokb, span_ids, span_type_ids, type_table,
                                        pooledA, validf);
  // enh = pooled @ Wp + bp
  gemm_kernel<2><<<(NSEG / BM) * (H / BN), 256, 0, stream>>>(
      pooledA, pooledA, H, Wpt, bp, NSEG, H, H,
      nullptr, enh, nullptr, nullptr, nullptr, nullptr, nullptr, nullptr);
  // norm (into h1 buffer) + span_mask
  ln_kernel<<<BTOK, 256, 0, stream>>>(tokb, enh, span_ids, validf, ln_g, ln_b, h1, outM);
  // gate + combined
  gemm_kernel<3><<<(BTOK / BM) * (H / BN), 256, 0, stream>>>(
      tokb, h1, H, Wgt, bg, BTOK, H, 2 * H,
      nullptr, nullptr, span_ids, validf, tokb, enh, outC, outG);
}

// Round 6
// 1537.960 us; speedup vs baseline: 1.0042x; 1.0042x over previous
//
#include <hip/hip_runtime.h>
#include <stdint.h>

#define H 2048
#define BTOK 16384   // B*S
#define NSEG 2048    // B*SPANS_PER_ITEM
#define SPANS 512
#define SEQ 4096

typedef __attribute__((ext_vector_type(8))) short bf16x8;
typedef __attribute__((ext_vector_type(4))) float f32x4;

__device__ __forceinline__ short f2bf(float f) {
  union { float f; uint32_t u; } x; x.f = f;
  uint32_t r = x.u + 0x7FFFu + ((x.u >> 16) & 1u);
  return (short)(uint16_t)(r >> 16);
}
__device__ __forceinline__ float bf2f(short h) {
  union { uint32_t u; float f; } x; x.u = ((uint32_t)(uint16_t)h) << 16;
  return x.f;
}

typedef __attribute__((address_space(1))) const void* gas_t;
typedef __attribute__((address_space(3))) void* las_t;
__device__ __forceinline__ void stage16(const void* g, void* l) {
  __builtin_amdgcn_global_load_lds((gas_t)g, (las_t)l, 16, 0, 0);
}

// ---------------- int64/int32 id detection + normalization ----------------
__global__ void detect_ids_kernel(const void* __restrict__ ids, int* __restrict__ flag) {
  __shared__ int any;
  if (threadIdx.x == 0) any = 0;
  __syncthreads();
  const long long* p = (const long long*)ids;
  int bad = 0;
  for (int i = threadIdx.x; i < 8192; i += 256) {   // 64KB: in-bounds for both layouts
    long long v = p[i];
    if (v < 0 || v >= 32000) bad = 1;
  }
  if (bad) any = 1;
  __syncthreads();
  if (threadIdx.x == 0) flag[0] = any;              // 1 -> storage is int32
}

__global__ void ids_norm_kernel(const void* __restrict__ ids, const int* __restrict__ flag,
                                int* __restrict__ ids32) {
  int i = blockIdx.x * 256 + threadIdx.x;
  if (flag[0]) {
    ids32[i] = ((const int*)ids)[i];
  } else {
    ids32[i] = (int)((const long long*)ids)[i];
  }
}

// ---------------- weight transpose + bf16 convert: Wt[n][k] = bf16(W[k][n]) ----------------
__global__ __launch_bounds__(256) void wconv_kernel(const float* __restrict__ W,
                                                    short* __restrict__ Wt, int K, int N) {
  __shared__ float t[32][33];
  int nt = N >> 5;
  int ti = blockIdx.x / nt;  // K tile
  int tj = blockIdx.x % nt;  // N tile
  int x = threadIdx.x & 31;
  int y = threadIdx.x >> 5;  // 0..7
  #pragma unroll
  for (int yy = 0; yy < 32; yy += 8)
    t[yy + y][x] = W[(size_t)(ti * 32 + yy + y) * N + tj * 32 + x];
  __syncthreads();
  #pragma unroll
  for (int yy = 0; yy < 32; yy += 8)
    Wt[(size_t)(tj * 32 + yy + y) * K + ti * 32 + x] = f2bf(t[x][yy + y]);
}

// ---------------- embedding gather -> bf16 ----------------
__global__ __launch_bounds__(256) void embed_kernel(const int* __restrict__ ids32,
                                                    const float* __restrict__ table,
                                                    short* __restrict__ emb) {
  int m = blockIdx.x;
  int row = ids32[m];
  const float4* src = (const float4*)(table + (size_t)row * H) + threadIdx.x * 2;
  float4 a = src[0], b = src[1];
  bf16x8 o;
  o[0] = f2bf(a.x); o[1] = f2bf(a.y); o[2] = f2bf(a.z); o[3] = f2bf(a.w);
  o[4] = f2bf(b.x); o[5] = f2bf(b.y); o[6] = f2bf(b.z); o[7] = f2bf(b.w);
  *(bf16x8*)(emb + (size_t)m * H + threadIdx.x * 8) = o;
}

// ---------------- MFMA GEMM: C[m,n] = A[m,:K] @ B[:K,n], Bt is [N][K] bf16 ----------------
// EPI 0: GELU -> bf16    EPI 1: + emb residual -> bf16    EPI 2: plain -> bf16
// EPI 3: gate = sigmoid(x)*mask; combined = (1-g)*tok + g*span_emb; write f32 outs
#define BM 128
#define BN 128
#define BK 32

template<int EPI>
__global__ __launch_bounds__(256, 2) void gemm_kernel(
    const short* __restrict__ A, const short* __restrict__ A2, int K1,
    const short* __restrict__ Bt, const float* __restrict__ bias,
    int M, int N, int K,
    const short* __restrict__ embres, short* __restrict__ outb,
    const int* __restrict__ span_ids, const int* __restrict__ valid,
    const short* __restrict__ tokp, const short* __restrict__ enh,
    float* __restrict__ outC, float* __restrict__ outG) {
  // Double-buffered LDS (2-phase pipeline, T3-minimum): stage tile t+1 while
  // computing tile t; ONE __syncthreads per K-step (its implicit vmcnt(0)
  // covers the stage, lgkmcnt(0) covers the ds_reads).
  __shared__ __align__(16) short lA[2][BM * BK];
  __shared__ __align__(16) short lB[2][BN * BK];
  const int tid = threadIdx.x;
  const int wave = tid >> 6;
  const int lane = tid & 63;
  const int MB = M / BM;
  const int NB = N / BN;
  // Bijective XCD swizzle (T1) + A-panel-major order: consecutive blocks in an
  // XCD chunk share the same bm (1MB A-panel stays in that XCD's L2) and sweep
  // bn. Previous bm-fast order put ALL of A (134MB) in each XCD's working set
  // -> FETCH 1.19GB on gemm<3>.
  const int nwg = gridDim.x;
  const int cpx = nwg >> 3;
  const int swz = (blockIdx.x & 7) * cpx + (blockIdx.x >> 3);
  const int bm = swz / NB;
  const int bn = swz % NB;
  const int wm = wave >> 1, wn = wave & 1;

  f32x4 zero4 = {0.f, 0.f, 0.f, 0.f};
  f32x4 acc[4][4];
  #pragma unroll
  for (int i = 0; i < 4; ++i)
    #pragma unroll
    for (int j = 0; j < 4; ++j) acc[i][j] = zero4;

  const int sr = wave * 32 + (lane >> 2);  // staging row within tile (j=0 group)
  const int kc = (lane & 3) * 8;           // staging k-chunk (bf16 elems)
  const int ar0 = bm * BM + sr;
  const int br0 = bn * BN + sr;

  const int clr = lane & 15;          // fragment row (A) / col (B) / col (C)
  const int clk = (lane >> 4) * 8;    // fragment k offset

  // wave-uniform LDS strip bases + wave-uniform global operand select
  auto STAGE = [&](int buf, int kk) {
    const short* Ab; int ko, as_;
    if (kk < K1) { Ab = A; ko = kk; as_ = K1; }
    else         { Ab = A2; ko = kk - K1; as_ = K - K1; }
    stage16(Ab + (size_t)ar0 * as_ + ko + kc, &lA[buf][(wave * 32) * BK]);
    stage16(Ab + (size_t)(ar0 + 16) * as_ + ko + kc, &lA[buf][(wave * 32 + 16) * BK]);
    stage16(Bt + (size_t)br0 * K + kk + kc, &lB[buf][(wave * 32) * BK]);
    stage16(Bt + (size_t)(br0 + 16) * K + kk + kc, &lB[buf][(wave * 32 + 16) * BK]);
  };
  auto COMPUTE = [&](int buf) {
    bf16x8 af[4], bfr[4];
    #pragma unroll
    for (int mi = 0; mi < 4; ++mi)
      af[mi] = *(const bf16x8*)&lA[buf][(wm * 64 + mi * 16 + clr) * BK + clk];
    #pragma unroll
    for (int ni = 0; ni < 4; ++ni)
      bfr[ni] = *(const bf16x8*)&lB[buf][(wn * 64 + ni * 16 + clr) * BK + clk];
    #pragma unroll
    for (int mi = 0; mi < 4; ++mi)
      #pragma unroll
      for (int ni = 0; ni < 4; ++ni)
        acc[mi][ni] = __builtin_amdgcn_mfma_f32_16x16x32_bf16(af[mi], bfr[ni], acc[mi][ni], 0, 0, 0);
  };

  STAGE(0, 0);
  __syncthreads();
  int cur = 0;
  for (int kk = BK; kk < K; kk += BK) {
    STAGE(cur ^ 1, kk);   // issue next-tile loads BEFORE compute: latency hides under MFMA
    COMPUTE(cur);
    __syncthreads();      // vmcnt(0): next tile landed; lgkmcnt+barrier: reads of cur done
    cur ^= 1;
  }
  COMPUTE(cur);           // last tile (no prefetch)

  const int lg = lane >> 4;
  const int rb = bm * BM + wm * 64;
  const int cb = bn * BN + wn * 64;
  #pragma unroll
  for (int ni = 0; ni < 4; ++ni) {
    const int c = cb + ni * 16 + clr;
    const float bv = bias[c];
    #pragma unroll
    for (int mi = 0; mi < 4; ++mi) {
      const int r0e = rb + mi * 16 + lg * 4;
      #pragma unroll
      for (int j = 0; j < 4; ++j) {
        const int r = r0e + j;
        float x = acc[mi][ni][j] + bv;
        if (EPI == 0) {
          float g = 0.5f * x * (1.f + erff(x * 0.70710678118654752f));
          outb[(size_t)r * N + c] = f2bf(g);
        } else if (EPI == 1) {
          x += bf2f(embres[(size_t)r * N + c]);
          outb[(size_t)r * N + c] = f2bf(x);
        } else if (EPI == 2) {
          outb[(size_t)r * N + c] = f2bf(x);
        } else {
          const int seg = ((r >> 12) << 9) + span_ids[r];
          const int v = valid[seg];
          const float g = v ? (1.f / (1.f + __expf(-x))) : 0.f;
          const float te = bf2f(tokp[(size_t)r * H + c]);
          const float se = v ? bf2f(enh[(size_t)seg * H + c]) : te;
          outC[(size_t)r * H + c] = (1.f - g) * te + g * se;
          outG[(size_t)r * H + c] = g;
        }
      }
    }
  }
}

// ---------------- per-segment mean pool + type embedding ----------------
__global__ __launch_bounds__(256) void pool_kernel(
    const short* __restrict__ tok, const int* __restrict__ span_ids,
    const int* __restrict__ span_type_ids, const float* __restrict__ type_table,
    short* __restrict__ pooled, int* __restrict__ valid) {
  __shared__ int list[SEQ];
  __shared__ int nmatch;
  const int gseg = blockIdx.x;
  const int b = gseg >> 9;
  const int sp = gseg & 511;
  if (threadIdx.x == 0) nmatch = 0;
  __syncthreads();
  const int* sid = span_ids + b * SEQ;
  for (int s = threadIdx.x; s < SEQ; s += 256)
    if (sid[s] == sp) list[atomicAdd(&nmatch, 1)] = s;
  __syncthreads();
  const int n = nmatch;
  float accv[8] = {0, 0, 0, 0, 0, 0, 0, 0};
  const int d0 = threadIdx.x * 8;
  for (int i = 0; i < n; ++i) {
    const int s = list[i];
    bf16x8 v = *(const bf16x8*)(tok + ((size_t)(b * SEQ + s)) * H + d0);
    #pragma unroll
    for (int j = 0; j < 8; ++j) accv[j] += bf2f(v[j]);
  }
  const float inv = 1.f / (float)(n > 0 ? n : 1);
  const int t = span_type_ids[gseg];
  const float* tt = type_table + (size_t)t * H + d0;
  bf16x8 o;
  #pragma unroll
  for (int j = 0; j < 8; ++j) o[j] = f2bf(accv[j] * inv + tt[j]);
  *(bf16x8*)(pooled + (size_t)gseg * H + d0) = o;
  if (threadIdx.x == 0) valid[gseg] = (n > 1) ? 1 : 0;
}

// ---------------- per-token span_emb select + LayerNorm + mask ----------------
__global__ __launch_bounds__(256) void ln_kernel(
    const short* __restrict__ tok, const short* __restrict__ enh,
    const int* __restrict__ span_ids, const int* __restrict__ valid,
    const float* __restrict__ ln_g, const float* __restrict__ ln_b,
    short* __restrict__ normout, float* __restrict__ maskout) {
  const int m = blockIdx.x;
  const int b = m >> 12;
  const int seg = (b << 9) + span_ids[m];
  const int v = valid[seg];
  const short* src = v ? (enh + (size_t)seg * H) : (tok + (size_t)m * H);
  const int d0 = threadIdx.x * 8;
  bf16x8 raw = *(const bf16x8*)(src + d0);
  float vals[8];
  float s = 0.f, s2 = 0.f;
  #pragma unroll
  for (int j = 0; j < 8; ++j) { float f = bf2f(raw[j]); vals[j] = f; s += f; s2 += f * f; }
  #pragma unroll
  for (int o = 32; o > 0; o >>= 1) { s += __shfl_down(s, o); s2 += __shfl_down(s2, o); }
  __shared__ float red[8];
  const int wv = threadIdx.x >> 6, ln = threadIdx.x & 63;
  if (ln == 0) { red[wv] = s; red[4 + wv] = s2; }
  __syncthreads();
  const float S = red[0] + red[1] + red[2] + red[3];
  const float S2 = red[4] + red[5] + red[6] + red[7];
  const float mean = S * (1.f / H);
  const float var = S2 * (1.f / H) - mean * mean;
  const float rstd = rsqrtf(var + 1e-5f);
  const float4* gp = (const float4*)(ln_g + d0);
  const float4* bp = (const float4*)(ln_b + d0);
  float4 g0 = gp[0], g1 = gp[1], b0 = bp[0], b1 = bp[1];
  const float gs[8] = {g0.x, g0.y, g0.z, g0.w, g1.x, g1.y, g1.z, g1.w};
  const float bs[8] = {b0.x, b0.y, b0.z, b0.w, b1.x, b1.y, b1.z, b1.w};
  bf16x8 o;
  #pragma unroll
  for (int j = 0; j < 8; ++j) o[j] = f2bf((vals[j] - mean) * rstd * gs[j] + bs[j]);
  *(bf16x8*)(normout + (size_t)m * H + d0) = o;
  if (threadIdx.x == 0) maskout[m] = v ? 1.f : 0.f;
}

extern "C" void kernel_launch(void* const* d_in, const int* in_sizes, int n_in,
                              void* d_out, int out_size, void* d_ws, size_t ws_size,
                              hipStream_t stream) {
  const void* input_ids = d_in[0];
  const int* span_ids = (const int*)d_in[1];
  const int* span_type_ids = (const int*)d_in[2];
  const float* tok_table = (const float*)d_in[3];
  const float* W1 = (const float*)d_in[4];
  const float* b1 = (const float*)d_in[5];
  const float* W2 = (const float*)d_in[6];
  const float* b2 = (const float*)d_in[7];
  const float* type_table = (const float*)d_in[8];
  const float* Wp = (const float*)d_in[9];
  const float* bp = (const float*)d_in[10];
  const float* ln_g = (const float*)d_in[11];
  const float* ln_b = (const float*)d_in[12];
  const float* Wg = (const float*)d_in[13];
  const float* bg = (const float*)d_in[14];

  char* ws = (char*)d_ws;
  size_t off = 0;
  auto alloc = [&](size_t bytes) -> void* {
    void* p = ws + off;
    off += (bytes + 255) & ~(size_t)255;
    return p;
  };
  short* emb = (short*)alloc((size_t)BTOK * H * 2);
  short* h1 = (short*)alloc((size_t)BTOK * H * 2);   // reused as `norm` after gemm2
  short* tokb = (short*)alloc((size_t)BTOK * H * 2);
  short* W1t = (short*)alloc((size_t)H * H * 2);
  short* W2t = (short*)alloc((size_t)H * H * 2);
  short* Wpt = (short*)alloc((size_t)H * H * 2);
  short* Wgt = (short*)alloc((size_t)2 * H * H * 2);
  short* pooledA = (short*)alloc((size_t)NSEG * H * 2);
  short* enh = (short*)alloc((size_t)NSEG * H * 2);
  int* validf = (int*)alloc(NSEG * 4);
  int* ids32 = (int*)alloc(BTOK * 4);
  int* flag = (int*)alloc(256);

  float* outC = (float*)d_out;
  float* outG = outC + (size_t)BTOK * H;
  float* outM = outG + (size_t)BTOK * H;

  detect_ids_kernel<<<1, 256, 0, stream>>>(input_ids, flag);
  ids_norm_kernel<<<BTOK / 256, 256, 0, stream>>>(input_ids, flag, ids32);
  wconv_kernel<<<(H / 32) * (H / 32), 256, 0, stream>>>(W1, W1t, H, H);
  wconv_kernel<<<(H / 32) * (H / 32), 256, 0, stream>>>(W2, W2t, H, H);
  wconv_kernel<<<(H / 32) * (H / 32), 256, 0, stream>>>(Wp, Wpt, H, H);
  wconv_kernel<<<(2 * H / 32) * (H / 32), 256, 0, stream>>>(Wg, Wgt, 2 * H, H);
  embed_kernel<<<BTOK, 256, 0, stream>>>(ids32, tok_table, emb);

  // h1 = gelu(emb @ W1 + b1)
  gemm_kernel<0><<<(BTOK / BM) * (H / BN), 256, 0, stream>>>(
      emb, emb, H, W1t, b1, BTOK, H, H,
      nullptr, h1, nullptr, nullptr, nullptr, nullptr, nullptr, nullptr);
  // tok = emb + h1 @ W2 + b2
  gemm_kernel<1><<<(BTOK / BM) * (H / BN), 256, 0, stream>>>(
      h1, h1, H, W2t, b2, BTOK, H, H,
      emb, tokb, nullptr, nullptr, nullptr, nullptr, nullptr, nullptr);
  // pooled+type, valid
  pool_kernel<<<NSEG, 256, 0, stream>>>(tokb, span_ids, span_type_ids, type_table,
                                        pooledA, validf);
  // enh = pooled @ Wp + bp
  gemm_kernel<2><<<(NSEG / BM) * (H / BN), 256, 0, stream>>>(
      pooledA, pooledA, H, Wpt, bp, NSEG, H, H,
      nullptr, enh, nullptr, nullptr, nullptr, nullptr, nullptr, nullptr);
  // norm (into h1 buffer) + span_mask
  ln_kernel<<<BTOK, 256, 0, stream>>>(tokb, enh, span_ids, validf, ln_g, ln_b, h1, outM);
  // gate + combined
  gemm_kernel<3><<<(BTOK / BM) * (H / BN), 256, 0, stream>>>(
      tokb, h1, H, Wgt, bg, BTOK, H, 2 * H,
      nullptr, nullptr, span_ids, validf, tokb, enh, outC, outG);
}